// Round 2
// baseline (673.721 us; speedup 1.0000x reference)
//
#include <hip/hip_runtime.h>

// NTM cell forward. Inputs/outputs float32; compared at bf16-grade tolerance.
// B=2048 N=256 M=64 U=512 IN=10 SHIFT=1 CLIP=20
// Outputs flat (f32): y_t[B*512] | m_t[B*256*64] | R_t[B*64] | w_read[B*256] | w_write[B*256]

using u16 = unsigned short;

__device__ __forceinline__ float bf2f(u16 s){ union{float f;unsigned u;}v; v.u=((unsigned)s)<<16; return v.f; }
__device__ __forceinline__ u16 f2bf(float f){ union{float f;unsigned u;}v; v.f=f; unsigned r=v.u+0x7fffu+((v.u>>16)&1u); return (u16)(r>>16); }
__device__ __forceinline__ void bfpair(unsigned pr, float&a, float&b){ union{float f;unsigned u;}x,y; x.u=pr<<16; y.u=pr&0xffff0000u; a=x.f; b=y.f; }
__device__ __forceinline__ unsigned packbf(float a, float b){ return (unsigned)f2bf(a) | ((unsigned)f2bf(b)<<16); }
__device__ __forceinline__ float sigm(float x){ return 1.f/(1.f+expf(-x)); }
__device__ __forceinline__ float softplus_(float x){ return fmaxf(x,0.f)+log1pf(expf(-fabsf(x))); }

// ---------------- K1: h_prep = R0 @ Wprep + bprep  (B,64)@(64,512) ----------------
__global__ __launch_bounds__(256) void k_hprep(const float* __restrict__ R0, const float* __restrict__ Wprep,
                                               const float* __restrict__ bprep, float* __restrict__ hprep){
    int flat = blockIdx.x*256 + threadIdx.x;   // B*512 total
    int b = flat >> 9, u = flat & 511;
    float acc = bprep[u];
    const float* r = R0 + b*64;
    #pragma unroll 8
    for(int m=0;m<64;m++) acc += r[m] * Wprep[m*512+u];
    hprep[flat] = acc;
}

// ------------- K2: z = [x,hprep]@Wx + H0@Wh + bl; LSTM gates -> h (clipped) -------------
// grid: (B/8, 4), block 128. Each thread owns one u of a 128-wide u-tile, 4 gates x 8 batches.
__global__ __launch_bounds__(128) void k_lstm(const float* __restrict__ x, const float* __restrict__ hprep,
                                              const float* __restrict__ H0, const float* __restrict__ C0,
                                              const float* __restrict__ Wx, const float* __restrict__ Wh,
                                              const float* __restrict__ bl, float* __restrict__ h_ws){
    __shared__ float a_lds[8*524];
    int tid = threadIdx.x;
    int b0  = blockIdx.x*8;
    int u   = blockIdx.y*128 + tid;
    float acc[8][4];
    #pragma unroll
    for(int bb=0;bb<8;bb++){ acc[bb][0]=0.f; acc[bb][1]=0.f; acc[bb][2]=0.f; acc[bb][3]=0.f; }

    // phase 1: A = concat(x, hprep)  (522 cols), W = Wx (522 x 2048)
    for(int idx=tid; idx<8*522; idx+=128){
        int bb = idx/522; int k = idx - bb*522;
        float v = (k<10) ? x[(b0+bb)*10+k] : hprep[(b0+bb)*512 + (k-10)];
        a_lds[bb*524+k] = v;
    }
    __syncthreads();
    for(int k=0;k<520;k+=4){
        float areg[8][4];
        #pragma unroll
        for(int bb=0;bb<8;bb++){
            #pragma unroll
            for(int kk=0;kk<4;kk++) areg[bb][kk] = a_lds[bb*524+k+kk];
        }
        #pragma unroll
        for(int kk=0;kk<4;kk++){
            const float* wr = Wx + (k+kk)*2048;
            float wi=wr[u], wf=wr[512+u], wg=wr[1024+u], wo=wr[1536+u];
            #pragma unroll
            for(int bb=0;bb<8;bb++){
                float a = areg[bb][kk];
                acc[bb][0]+=a*wi; acc[bb][1]+=a*wf; acc[bb][2]+=a*wg; acc[bb][3]+=a*wo;
            }
        }
    }
    for(int k=520;k<522;k++){
        const float* wr = Wx + k*2048;
        float wi=wr[u], wf=wr[512+u], wg=wr[1024+u], wo=wr[1536+u];
        #pragma unroll
        for(int bb=0;bb<8;bb++){
            float a = a_lds[bb*524+k];
            acc[bb][0]+=a*wi; acc[bb][1]+=a*wf; acc[bb][2]+=a*wg; acc[bb][3]+=a*wo;
        }
    }
    __syncthreads();
    // phase 2: A = H0 (512), W = Wh (512 x 2048)
    for(int idx=tid; idx<8*512; idx+=128){
        int bb = idx>>9, k = idx&511;
        a_lds[bb*524+k] = H0[(b0+bb)*512+k];
    }
    __syncthreads();
    for(int k=0;k<512;k+=4){
        float areg[8][4];
        #pragma unroll
        for(int bb=0;bb<8;bb++){
            #pragma unroll
            for(int kk=0;kk<4;kk++) areg[bb][kk] = a_lds[bb*524+k+kk];
        }
        #pragma unroll
        for(int kk=0;kk<4;kk++){
            const float* wr = Wh + (k+kk)*2048;
            float wi=wr[u], wf=wr[512+u], wg=wr[1024+u], wo=wr[1536+u];
            #pragma unroll
            for(int bb=0;bb<8;bb++){
                float a = areg[bb][kk];
                acc[bb][0]+=a*wi; acc[bb][1]+=a*wf; acc[bb][2]+=a*wg; acc[bb][3]+=a*wo;
            }
        }
    }
    // epilogue: gates
    float bi = bl[u], bf_ = bl[512+u], bg = bl[1024+u], bo_ = bl[1536+u];
    #pragma unroll
    for(int bb=0;bb<8;bb++){
        int b = b0+bb;
        float zi = acc[bb][0]+bi, zf = acc[bb][1]+bf_, zg = acc[bb][2]+bg, zo = acc[bb][3]+bo_;
        float c  = sigm(zf)*C0[b*512+u] + sigm(zi)*tanhf(zg);
        float hv = sigm(zo)*tanhf(c);
        hv = fminf(fmaxf(hv,-20.f),20.f);
        h_ws[b*512+u] = hv;
    }
}

// ------------- K3: r_out = h@Wr+br (70 cols), w_out = h@Ww+bw (198 cols) -------------
// grid B/8, block 320 (threads 0..69 -> Wr cols, 70..267 -> Ww cols)
__global__ __launch_bounds__(320) void k_heads(const float* __restrict__ h_ws,
                                               const float* __restrict__ Wr, const float* __restrict__ br,
                                               const float* __restrict__ Ww, const float* __restrict__ bw,
                                               float* __restrict__ rout, float* __restrict__ wout){
    __shared__ float hl[8*512];
    int tid = threadIdx.x; int b0 = blockIdx.x*8;
    for(int idx=tid; idx<8*512; idx+=320) hl[idx] = h_ws[b0*512+idx];
    __syncthreads();
    if(tid<268){
        float acc[8]={0,0,0,0,0,0,0,0};
        bool isr = tid<70;
        int c = isr ? tid : tid-70;
        const float* W = isr ? Wr : Ww;
        int ldw = isr ? 70 : 198;
        for(int k=0;k<512;k++){
            float wv = W[k*ldw + c];
            #pragma unroll
            for(int bb=0;bb<8;bb++) acc[bb] += hl[bb*512+k]*wv;
        }
        float bias = isr ? br[c] : bw[c];
        #pragma unroll
        for(int bb=0;bb<8;bb++){
            float v = acc[bb]+bias;
            if(isr) rout[(b0+bb)*70 + c] = v;
            else    wout[(b0+bb)*198 + c] = v;
        }
    }
}

// block reductions over 256 threads
__device__ __forceinline__ float blk_sum(float* red, int tid, float v){
    red[tid]=v; __syncthreads();
    for(int s=128;s>0;s>>=1){ if(tid<s) red[tid]+=red[tid+s]; __syncthreads(); }
    float r=red[0]; __syncthreads(); return r;
}
__device__ __forceinline__ float blk_max(float* red, int tid, float v){
    red[tid]=v; __syncthreads();
    for(int s=128;s>0;s>>=1){ if(tid<s) red[tid]=fmaxf(red[tid],red[tid+s]); __syncthreads(); }
    float r=red[0]; __syncthreads(); return r;
}

// ------------- K4: per-b fused addressing (both heads) + R_t + m_t -------------
// grid B, block 256 (thread = memory slot n). m0[b] staged in LDS as bf16, stride 66.
// bf16 staging error ~2^-9 relative, well under the 6e-3 comparison threshold.
__global__ __launch_bounds__(256) void k_addr(const float* __restrict__ m0, const float* __restrict__ A0,
                                              const float* __restrict__ rout, const float* __restrict__ wout,
                                              float* __restrict__ rt_ws,
                                              float* __restrict__ out_mt, float* __restrict__ out_rt,
                                              float* __restrict__ out_wr, float* __restrict__ out_ww){
    __shared__ u16   m0h[256*66];
    __shared__ float red[256];
    __shared__ float kk_s[64];
    __shared__ float wg_s[256];
    __shared__ float wsel[2][256];
    __shared__ float mnorm[256];
    __shared__ float sc[6];        // s0, s1, s2, beta, g, gamma  (see below)
    __shared__ float dv[64], avv[64];
    int tid = threadIdx.x; int b = blockIdx.x;

    // stage m0[b] (256x64 f32 = 64KB global) -> LDS bf16, coalesced float4 loads
    const float* mb = m0 + (size_t)b*16384;
    #pragma unroll
    for(int i=0;i<16;i++){
        int e = i*1024 + tid*4;
        float4 v = *(const float4*)(mb + e);
        int n = e>>6, mcol = e&63;
        unsigned* dst = (unsigned*)&m0h[n*66 + mcol];
        dst[0] = packbf(v.x, v.y);
        dst[1] = packbf(v.z, v.w);
    }
    __syncthreads();
    // m_norm[n]
    {
        float s=0.f; const u16* row=&m0h[tid*66];
        #pragma unroll 8
        for(int m=0;m<64;m+=2){ float v0,v1; bfpair(*(const unsigned*)&row[m],v0,v1); s+=v0*v0+v1*v1; }
        mnorm[tid]=sqrtf(s);
    }
    __syncthreads();

    for(int head=0; head<2; head++){
        const float* hd = head ? (wout + b*198) : (rout + b*70);
        if(tid<64) kk_s[tid] = tanhf(hd[tid]);
        if(tid==64){
            sc[0]=softplus_(hd[64]);          // beta
            sc[1]=sigm(hd[65]);               // g
            float e0=hd[66],e1=hd[67],e2=hd[68];
            float mx=fmaxf(e0,fmaxf(e1,e2));
            float x0=expf(e0-mx),x1=expf(e1-mx),x2=expf(e2-mx);
            float ss=x0+x1+x2;
            sc[2]=x0/ss; sc[3]=x1/ss; sc[4]=x2/ss;
            sc[5]=softplus_(hd[69]);          // gamma
        }
        __syncthreads();
        float kv=(tid<64)?kk_s[tid]:0.f;
        float knorm = sqrtf(blk_sum(red,tid,kv*kv));
        // ip[n] = m0[n,:] . k
        float ip=0.f; const u16* row=&m0h[tid*66];
        #pragma unroll 8
        for(int m=0;m<64;m+=2){ float v0,v1; bfpair(*(const unsigned*)&row[m],v0,v1); ip += v0*kk_s[m]+v1*kk_s[m+1]; }
        float K = ip/(knorm*mnorm[tid] + 1e-8f);
        float e = sc[0]*K;
        float mx = blk_max(red,tid,e);
        float p = expf(e-mx);
        float wc = p / blk_sum(red,tid,p);
        float a = A0[head*524288 + b*256 + tid];
        float g = sc[1];
        float wg = g*wc + (1.f-g)*a;
        wg_s[tid]=wg; __syncthreads();
        float conv = sc[2]*wg + sc[3]*wg_s[(tid+255)&255] + sc[4]*wg_s[(tid+1)&255];
        conv = fmaxf(conv, 1e-35f);
        float wsh = expf(sc[5]*logf(conv));
        float w = wsh / blk_sum(red,tid,wsh);
        wsel[head][tid]=w;
        (head ? out_ww : out_wr)[b*256 + tid] = w;
        __syncthreads();
    }
    // R_t[m] = sum_n w_read[n]*m0[n][m]
    {
        int chunk=tid>>6, m=tid&63;
        float p=0.f;
        #pragma unroll 8
        for(int j=0;j<64;j++){ int n=chunk*64+j; p += wsel[0][n]*bf2f(m0h[n*66+m]); }
        red[tid]=p; __syncthreads();
        if(tid<64){
            float rt = red[tid]+red[tid+64]+red[tid+128]+red[tid+192];
            rt_ws[b*64+tid]=rt;
            out_rt[b*64+tid]=rt;
        }
        __syncthreads();
    }
    // m_t = m0*(1 - ww*del) + ww*add
    {
        const float* wob = wout + b*198;
        if(tid<64){ dv[tid]=sigm(wob[70+tid]); avv[tid]=tanhf(wob[134+tid]); }
        __syncthreads();
        #pragma unroll
        for(int i=0;i<16;i++){
            int e = i*1024 + tid*4; int n=e>>6; int mcol=e&63;
            float ww = wsel[1][n];
            const unsigned* src = (const unsigned*)&m0h[n*66+mcol];
            float v0,v1,v2,v3;
            bfpair(src[0],v0,v1);
            bfpair(src[1],v2,v3);
            float4 o;
            o.x = v0*(1.f-ww*dv[mcol])   + ww*avv[mcol];
            o.y = v1*(1.f-ww*dv[mcol+1]) + ww*avv[mcol+1];
            o.z = v2*(1.f-ww*dv[mcol+2]) + ww*avv[mcol+2];
            o.w = v3*(1.f-ww*dv[mcol+3]) + ww*avv[mcol+3];
            *(float4*)(out_mt + (size_t)b*16384 + e) = o;
        }
    }
}

// ------------- K5: y = clip(concat(h,R_t)@Wo + bo) -------------
__global__ __launch_bounds__(512) void k_out(const float* __restrict__ h_ws, const float* __restrict__ rt_ws,
                                             const float* __restrict__ Wo, const float* __restrict__ bo,
                                             float* __restrict__ y){
    __shared__ float al[8*576];
    int tid=threadIdx.x; int b0=blockIdx.x*8;
    for(int idx=tid; idx<8*576; idx+=512){
        int bb=idx/576, k=idx-bb*576;
        al[idx] = (k<512) ? h_ws[(b0+bb)*512+k] : rt_ws[(b0+bb)*64 + (k-512)];
    }
    __syncthreads();
    float acc[8]={0,0,0,0,0,0,0,0};
    int u=tid;
    for(int k=0;k<576;k+=4){
        float areg[8][4];
        #pragma unroll
        for(int bb=0;bb<8;bb++){
            #pragma unroll
            for(int kk=0;kk<4;kk++) areg[bb][kk] = al[bb*576+k+kk];
        }
        #pragma unroll
        for(int kk=0;kk<4;kk++){
            float wv = Wo[(k+kk)*512 + u];
            #pragma unroll
            for(int bb=0;bb<8;bb++) acc[bb] += areg[bb][kk]*wv;
        }
    }
    float bias = bo[u];
    #pragma unroll
    for(int bb=0;bb<8;bb++){
        float v = acc[bb]+bias;
        v = fminf(fmaxf(v,-20.f),20.f);
        y[(b0+bb)*512 + u] = v;
    }
}

extern "C" void kernel_launch(void* const* d_in, const int* in_sizes, int n_in,
                              void* d_out, int out_size, void* d_ws, size_t ws_size,
                              hipStream_t stream) {
    const float* x     = (const float*)d_in[0];
    const float* H0    = (const float*)d_in[1];
    const float* C0    = (const float*)d_in[2];
    const float* m0    = (const float*)d_in[3];
    const float* R0    = (const float*)d_in[4];
    const float* A0    = (const float*)d_in[5];
    const float* Wprep = (const float*)d_in[6];
    const float* bprep = (const float*)d_in[7];
    const float* Wx    = (const float*)d_in[8];
    const float* Wh    = (const float*)d_in[9];
    const float* bl    = (const float*)d_in[10];
    const float* Wr    = (const float*)d_in[11];
    const float* br    = (const float*)d_in[12];
    const float* Ww    = (const float*)d_in[13];
    const float* bw    = (const float*)d_in[14];
    const float* Wo    = (const float*)d_in[15];
    const float* bo    = (const float*)d_in[16];

    float* ws    = (float*)d_ws;
    float* hprep = ws;              // B*512
    float* h     = ws + 1048576;    // B*512
    float* rout  = ws + 2097152;    // B*70
    float* wout  = ws + 2240512;    // B*198
    float* rt    = ws + 2646016;    // B*64

    float* out    = (float*)d_out;
    float* out_y  = out;              // 1048576
    float* out_mt = out + 1048576;    // 33554432
    float* out_rt = out + 34603008;   // 131072
    float* out_wr = out + 34734080;   // 524288
    float* out_ww = out + 35258368;   // 524288

    hipLaunchKernelGGL(k_hprep, dim3(4096),    dim3(256), 0, stream, R0, Wprep, bprep, hprep);
    hipLaunchKernelGGL(k_lstm,  dim3(256,4),   dim3(128), 0, stream, x, hprep, H0, C0, Wx, Wh, bl, h);
    hipLaunchKernelGGL(k_heads, dim3(256),     dim3(320), 0, stream, h, Wr, br, Ww, bw, rout, wout);
    hipLaunchKernelGGL(k_addr,  dim3(2048),    dim3(256), 0, stream, m0, A0, rout, wout, rt,
                       out_mt, out_rt, out_wr, out_ww);
    hipLaunchKernelGGL(k_out,   dim3(256),     dim3(512), 0, stream, h, rt, Wo, bo, out_y);
}

// Round 3
// 396.233 us; speedup vs baseline: 1.7003x; 1.7003x over previous
//
#include <hip/hip_runtime.h>

// NTM cell forward. f32 in/out, bf16 MFMA for all large GEMMs (tolerance is bf16-grade).
// B=2048 N=256 M=64 U=512 IN=10 SHIFT=1 CLIP=20
// Outputs flat (f32): y_t[B*512] | m_t[B*256*64] | R_t[B*64] | w_read[B*256] | w_write[B*256]

using u16   = unsigned short;
using bfrag = __attribute__((ext_vector_type(8))) short;   // 8 bf16 (4 VGPRs)
using f4    = __attribute__((ext_vector_type(4))) float;   // MFMA accumulator

__device__ __forceinline__ float bf2f(u16 s){ union{float f;unsigned u;}v; v.u=((unsigned)s)<<16; return v.f; }
__device__ __forceinline__ u16 f2bf(float f){ union{float f;unsigned u;}v; v.f=f; unsigned r=v.u+0x7fffu+((v.u>>16)&1u); return (u16)(r>>16); }
__device__ __forceinline__ void bfpair(unsigned pr, float&a, float&b){ union{float f;unsigned u;}x,y; x.u=pr<<16; y.u=pr&0xffff0000u; a=x.f; b=y.f; }
__device__ __forceinline__ unsigned packbf(float a, float b){ return (unsigned)f2bf(a) | ((unsigned)f2bf(b)<<16); }
__device__ __forceinline__ float sigm(float x){ return 1.f/(1.f+expf(-x)); }
__device__ __forceinline__ float softplus_(float x){ return fmaxf(x,0.f)+log1pf(expf(-fabsf(x))); }

// async global->LDS, 16B per lane; lptr must be wave-uniform (HW adds lane*16)
__device__ __forceinline__ void gld16(const u16* g, u16* l){
    __builtin_amdgcn_global_load_lds((const __attribute__((address_space(1))) unsigned*)g,
                                     (__attribute__((address_space(3))) unsigned*)l, 16, 0, 0);
}

// ======================= weight transpose/convert kernels =======================
// dst layout: Wt[n][k] bf16 (so A and B MFMA fragments load identically, gemm_bt style)

__global__ __launch_bounds__(256) void k_wt_lstm(const float* __restrict__ Wx, const float* __restrict__ Wh,
                                                 u16* __restrict__ Wt){
    __shared__ float t[32][33];
    int n0 = blockIdx.x*32, k0 = blockIdx.y*32;           // n<2048, k<1056
    int tx = threadIdx.x & 31, ty = threadIdx.x >> 5;     // ty 0..7
    #pragma unroll
    for(int r=0;r<4;r++){
        int k = k0 + ty*4 + r, n = n0 + tx;
        float v;
        if(k < 522)       v = Wx[k*2048 + n];
        else if(k < 1034) v = Wh[(k-522)*2048 + n];
        else              v = 0.f;
        t[ty*4+r][tx] = v;
    }
    __syncthreads();
    #pragma unroll
    for(int r=0;r<4;r++){
        int n = n0 + ty*4 + r, k = k0 + tx;
        Wt[n*1056 + k] = f2bf(t[tx][ty*4+r]);
    }
}

__global__ __launch_bounds__(256) void k_wt_heads(const float* __restrict__ Wr, const float* __restrict__ Ww,
                                                  u16* __restrict__ Wt){
    __shared__ float t[32][33];
    int n0 = blockIdx.x*32, k0 = blockIdx.y*32;           // n<384 (pad), k<512
    int tx = threadIdx.x & 31, ty = threadIdx.x >> 5;
    #pragma unroll
    for(int r=0;r<4;r++){
        int k = k0 + ty*4 + r, n = n0 + tx;
        float v;
        if(n < 70)        v = Wr[k*70 + n];
        else if(n < 268)  v = Ww[k*198 + (n-70)];
        else              v = 0.f;
        t[ty*4+r][tx] = v;
    }
    __syncthreads();
    #pragma unroll
    for(int r=0;r<4;r++){
        int n = n0 + ty*4 + r, k = k0 + tx;
        Wt[n*512 + k] = f2bf(t[tx][ty*4+r]);
    }
}

__global__ __launch_bounds__(256) void k_wt_out(const float* __restrict__ Wo, u16* __restrict__ Wt){
    __shared__ float t[32][33];
    int n0 = blockIdx.x*32, k0 = blockIdx.y*32;           // n<512, k<576
    int tx = threadIdx.x & 31, ty = threadIdx.x >> 5;
    #pragma unroll
    for(int r=0;r<4;r++){
        int k = k0 + ty*4 + r, n = n0 + tx;
        t[ty*4+r][tx] = Wo[k*512 + n];
    }
    __syncthreads();
    #pragma unroll
    for(int r=0;r<4;r++){
        int n = n0 + ty*4 + r, k = k0 + tx;
        Wt[n*576 + k] = f2bf(t[tx][ty*4+r]);
    }
}

// ======================= A-matrix build: [x | hprep | H0 | 0pad], bf16, lda=1056 =======================
__global__ __launch_bounds__(256) void k_abuild(const float* __restrict__ x, const float* __restrict__ H0,
                                                const float* __restrict__ R0, const float* __restrict__ Wprep,
                                                const float* __restrict__ bprep, u16* __restrict__ A){
    int flat = blockIdx.x*256 + threadIdx.x;   // B*512
    int b = flat >> 9, u = flat & 511;
    u16* Ab = A + (size_t)b*1056;
    // hprep = R0 @ Wprep + bprep
    float acc = bprep[u];
    const float* r = R0 + b*64;
    #pragma unroll 8
    for(int m=0;m<64;m++) acc += r[m] * Wprep[m*512+u];
    Ab[10+u] = f2bf(acc);
    Ab[522+u] = f2bf(H0[b*512+u]);
    if(u<10) Ab[u] = f2bf(x[b*10+u]);
    if(u<22) Ab[1034+u] = 0;                   // zero K-pad 1034..1055
}

// ======================= MFMA GEMM core: 128x128 C tile, BK=32 =======================
// A: M x K row-major bf16 (lda), Bt: N x K row-major bf16 (ldb). 256 threads = 4 waves,
// wave (wr,wc) owns 64x64 = 4x4 of 16x16x32 MFMAs. m97 2-barrier structure.
__device__ __forceinline__ void gemm128(const u16* __restrict__ A, int lda,
                                        const u16* __restrict__ Bt, int ldb,
                                        int bm, int bn, int kiters,
                                        u16* Al, u16* Bl, f4 acc[4][4]){
    int tid = threadIdx.x, w = tid>>6, lane = tid&63, quad = lane>>4, l16 = lane&15;
    int wr = w>>1, wc = w&1;
    f4 z4 = {0.f,0.f,0.f,0.f};
    #pragma unroll
    for(int i=0;i<4;i++)
        #pragma unroll
        for(int j=0;j<4;j++) acc[i][j] = z4;
    // staging chunks: 512 x 16B per tile, 2 per thread; chunk c -> row c>>2, kchunk c&3
    int rA0 = tid>>2, kc = tid&3;        // q=0 rows 0..63
    int rA1 = rA0 + 64;                  // q=1 rows 64..127
    const u16* ga0 = A  + (size_t)(bm+rA0)*lda + kc*8;
    const u16* ga1 = A  + (size_t)(bm+rA1)*lda + kc*8;
    const u16* gb0 = Bt + (size_t)(bn+rA0)*ldb + kc*8;
    const u16* gb1 = Bt + (size_t)(bn+rA1)*ldb + kc*8;
    u16* lA0 = Al + (w*64)*8;            // wave-uniform LDS bases (chunks w*64.., +lane*16B by HW)
    u16* lA1 = Al + (256 + w*64)*8;
    u16* lB0 = Bl + (w*64)*8;
    u16* lB1 = Bl + (256 + w*64)*8;
    for(int kt=0; kt<kiters; kt++){
        __syncthreads();
        gld16(ga0, lA0); gld16(ga1, lA1);
        gld16(gb0, lB0); gld16(gb1, lB1);
        ga0 += 32; ga1 += 32; gb0 += 32; gb1 += 32;
        __syncthreads();
        bfrag af[4], bf[4];
        #pragma unroll
        for(int i=0;i<4;i++) af[i] = *(const bfrag*)&Al[(wr*64 + i*16 + l16)*32 + quad*8];
        #pragma unroll
        for(int j=0;j<4;j++) bf[j] = *(const bfrag*)&Bl[(wc*64 + j*16 + l16)*32 + quad*8];
        #pragma unroll
        for(int i=0;i<4;i++)
            #pragma unroll
            for(int j=0;j<4;j++)
                acc[i][j] = __builtin_amdgcn_mfma_f32_16x16x32_bf16(af[i], bf[j], acc[i][j], 0, 0, 0);
    }
}
// C/D mapping (m89-verified): col = lane&15, row = quad*4 + reg.

// ------------- GEMM 1: z = A @ Wt_lstm^T  (2048 x 2048, K=1056), raw f32 store -------------
__global__ __launch_bounds__(256) void k_gemm_lstm(const u16* __restrict__ A, const u16* __restrict__ Wt,
                                                   float* __restrict__ z){
    __shared__ u16 Al[128*32], Bl[128*32];
    f4 acc[4][4];
    int bm = blockIdx.x*128, bn = blockIdx.y*128;
    gemm128(A, 1056, Wt, 1056, bm, bn, 33, Al, Bl, acc);
    int lane = threadIdx.x&63, quad = lane>>4, l16 = lane&15, w = threadIdx.x>>6;
    int wr = w>>1, wc = w&1;
    #pragma unroll
    for(int i=0;i<4;i++){
        #pragma unroll
        for(int j=0;j<4;j++){
            int col = bn + wc*64 + j*16 + l16;
            #pragma unroll
            for(int r=0;r<4;r++){
                int row = bm + wr*64 + i*16 + quad*4 + r;
                z[(size_t)row*2048 + col] = acc[i][j][r];
            }
        }
    }
}

// ------------- gates: z -> h (bf16 into A2 cols 0..511) -------------
__global__ __launch_bounds__(256) void k_gates(const float* __restrict__ z, const float* __restrict__ C0,
                                               const float* __restrict__ bl, u16* __restrict__ A2){
    int flat = blockIdx.x*256 + threadIdx.x;  // B*512
    int b = flat>>9, u = flat&511;
    const float* zb = z + (size_t)b*2048;
    float zi = zb[u]      + bl[u];
    float zf = zb[512+u]  + bl[512+u];
    float zg = zb[1024+u] + bl[1024+u];
    float zo = zb[1536+u] + bl[1536+u];
    float c  = sigm(zf)*C0[b*512+u] + sigm(zi)*tanhf(zg);
    float hv = sigm(zo)*tanhf(c);
    hv = fminf(fmaxf(hv,-20.f),20.f);
    A2[(size_t)b*576 + u] = f2bf(hv);
}

// ------------- GEMM 2: [rout|wout] = h @ Wt_h^T  (2048 x 268(pad 384), K=512) -------------
__global__ __launch_bounds__(256) void k_gemm_heads(const u16* __restrict__ A2, const u16* __restrict__ Wt,
                                                    const float* __restrict__ br, const float* __restrict__ bw,
                                                    float* __restrict__ rout, float* __restrict__ wout){
    __shared__ u16 Al[128*32], Bl[128*32];
    f4 acc[4][4];
    int bm = blockIdx.x*128, bn = blockIdx.y*128;
    gemm128(A2, 576, Wt, 512, bm, bn, 16, Al, Bl, acc);
    int lane = threadIdx.x&63, quad = lane>>4, l16 = lane&15, w = threadIdx.x>>6;
    int wr = w>>1, wc = w&1;
    #pragma unroll
    for(int i=0;i<4;i++){
        #pragma unroll
        for(int j=0;j<4;j++){
            int col = bn + wc*64 + j*16 + l16;
            if(col >= 268) continue;
            #pragma unroll
            for(int r=0;r<4;r++){
                int row = bm + wr*64 + i*16 + quad*4 + r;
                float v = acc[i][j][r];
                if(col < 70) rout[(size_t)row*70 + col]        = v + br[col];
                else         wout[(size_t)row*198 + (col-70)]  = v + bw[col-70];
            }
        }
    }
}

// ------------- GEMM 3: y = clip([h|R_t] @ Wt_o^T + bo)  (2048 x 512, K=576) -------------
__global__ __launch_bounds__(256) void k_gemm_out(const u16* __restrict__ A2, const u16* __restrict__ Wt,
                                                  const float* __restrict__ bo, float* __restrict__ y){
    __shared__ u16 Al[128*32], Bl[128*32];
    f4 acc[4][4];
    int bm = blockIdx.x*128, bn = blockIdx.y*128;
    gemm128(A2, 576, Wt, 576, bm, bn, 18, Al, Bl, acc);
    int lane = threadIdx.x&63, quad = lane>>4, l16 = lane&15, w = threadIdx.x>>6;
    int wr = w>>1, wc = w&1;
    #pragma unroll
    for(int i=0;i<4;i++){
        #pragma unroll
        for(int j=0;j<4;j++){
            int col = bn + wc*64 + j*16 + l16;
            float bias = bo[col];
            #pragma unroll
            for(int r=0;r<4;r++){
                int row = bm + wr*64 + i*16 + quad*4 + r;
                float v = acc[i][j][r] + bias;
                v = fminf(fmaxf(v,-20.f),20.f);
                y[(size_t)row*512 + col] = v;
            }
        }
    }
}

// block reductions over 256 threads
__device__ __forceinline__ float blk_sum(float* red, int tid, float v){
    red[tid]=v; __syncthreads();
    for(int s=128;s>0;s>>=1){ if(tid<s) red[tid]+=red[tid+s]; __syncthreads(); }
    float r=red[0]; __syncthreads(); return r;
}
__device__ __forceinline__ float blk_max(float* red, int tid, float v){
    red[tid]=v; __syncthreads();
    for(int s=128;s>0;s>>=1){ if(tid<s) red[tid]=fmaxf(red[tid],red[tid+s]); __syncthreads(); }
    float r=red[0]; __syncthreads(); return r;
}

// ------------- K4: per-b fused addressing (both heads) + R_t + m_t -------------
__global__ __launch_bounds__(256) void k_addr(const float* __restrict__ m0, const float* __restrict__ A0,
                                              const float* __restrict__ rout, const float* __restrict__ wout,
                                              u16* __restrict__ A2,
                                              float* __restrict__ out_mt, float* __restrict__ out_rt,
                                              float* __restrict__ out_wr, float* __restrict__ out_ww){
    __shared__ u16   m0h[256*66];
    __shared__ float red[256];
    __shared__ float kk_s[64];
    __shared__ float wg_s[256];
    __shared__ float wsel[2][256];
    __shared__ float mnorm[256];
    __shared__ float sc[6];
    __shared__ float dv[64], avv[64];
    int tid = threadIdx.x; int b = blockIdx.x;

    const float* mb = m0 + (size_t)b*16384;
    #pragma unroll
    for(int i=0;i<16;i++){
        int e = i*1024 + tid*4;
        float4 v = *(const float4*)(mb + e);
        int n = e>>6, mcol = e&63;
        unsigned* dst = (unsigned*)&m0h[n*66 + mcol];
        dst[0] = packbf(v.x, v.y);
        dst[1] = packbf(v.z, v.w);
    }
    __syncthreads();
    {
        float s=0.f; const u16* row=&m0h[tid*66];
        #pragma unroll 8
        for(int m=0;m<64;m+=2){ float v0,v1; bfpair(*(const unsigned*)&row[m],v0,v1); s+=v0*v0+v1*v1; }
        mnorm[tid]=sqrtf(s);
    }
    __syncthreads();

    for(int head=0; head<2; head++){
        const float* hd = head ? (wout + b*198) : (rout + b*70);
        if(tid<64) kk_s[tid] = tanhf(hd[tid]);
        if(tid==64){
            sc[0]=softplus_(hd[64]);
            sc[1]=sigm(hd[65]);
            float e0=hd[66],e1=hd[67],e2=hd[68];
            float mx=fmaxf(e0,fmaxf(e1,e2));
            float x0=expf(e0-mx),x1=expf(e1-mx),x2=expf(e2-mx);
            float ss=x0+x1+x2;
            sc[2]=x0/ss; sc[3]=x1/ss; sc[4]=x2/ss;
            sc[5]=softplus_(hd[69]);
        }
        __syncthreads();
        float kv=(tid<64)?kk_s[tid]:0.f;
        float knorm = sqrtf(blk_sum(red,tid,kv*kv));
        float ip=0.f; const u16* row=&m0h[tid*66];
        #pragma unroll 8
        for(int m=0;m<64;m+=2){ float v0,v1; bfpair(*(const unsigned*)&row[m],v0,v1); ip += v0*kk_s[m]+v1*kk_s[m+1]; }
        float K = ip/(knorm*mnorm[tid] + 1e-8f);
        float e = sc[0]*K;
        float mx = blk_max(red,tid,e);
        float p = expf(e-mx);
        float wc = p / blk_sum(red,tid,p);
        float a = A0[head*524288 + b*256 + tid];
        float g = sc[1];
        float wg = g*wc + (1.f-g)*a;
        wg_s[tid]=wg; __syncthreads();
        float conv = sc[2]*wg + sc[3]*wg_s[(tid+255)&255] + sc[4]*wg_s[(tid+1)&255];
        conv = fmaxf(conv, 1e-35f);
        float wsh = expf(sc[5]*logf(conv));
        float w = wsh / blk_sum(red,tid,wsh);
        wsel[head][tid]=w;
        (head ? out_ww : out_wr)[b*256 + tid] = w;
        __syncthreads();
    }
    // R_t
    {
        int chunk=tid>>6, m=tid&63;
        float p=0.f;
        #pragma unroll 8
        for(int j=0;j<64;j++){ int n=chunk*64+j; p += wsel[0][n]*bf2f(m0h[n*66+m]); }
        red[tid]=p; __syncthreads();
        if(tid<64){
            float rt = red[tid]+red[tid+64]+red[tid+128]+red[tid+192];
            out_rt[b*64+tid]=rt;
            A2[(size_t)b*576 + 512 + tid] = f2bf(rt);   // feed out-GEMM
        }
        __syncthreads();
    }
    // m_t
    {
        const float* wob = wout + b*198;
        if(tid<64){ dv[tid]=sigm(wob[70+tid]); avv[tid]=tanhf(wob[134+tid]); }
        __syncthreads();
        #pragma unroll
        for(int i=0;i<16;i++){
            int e = i*1024 + tid*4; int n=e>>6; int mcol=e&63;
            float ww = wsel[1][n];
            const unsigned* src = (const unsigned*)&m0h[n*66+mcol];
            float v0,v1,v2,v3;
            bfpair(src[0],v0,v1);
            bfpair(src[1],v2,v3);
            float4 o;
            o.x = v0*(1.f-ww*dv[mcol])   + ww*avv[mcol];
            o.y = v1*(1.f-ww*dv[mcol+1]) + ww*avv[mcol+1];
            o.z = v2*(1.f-ww*dv[mcol+2]) + ww*avv[mcol+2];
            o.w = v3*(1.f-ww*dv[mcol+3]) + ww*avv[mcol+3];
            *(float4*)(out_mt + (size_t)b*16384 + e) = o;
        }
    }
}

extern "C" void kernel_launch(void* const* d_in, const int* in_sizes, int n_in,
                              void* d_out, int out_size, void* d_ws, size_t ws_size,
                              hipStream_t stream) {
    const float* x     = (const float*)d_in[0];
    const float* H0    = (const float*)d_in[1];
    const float* C0    = (const float*)d_in[2];
    const float* m0    = (const float*)d_in[3];
    const float* R0    = (const float*)d_in[4];
    const float* A0    = (const float*)d_in[5];
    const float* Wprep = (const float*)d_in[6];
    const float* bprep = (const float*)d_in[7];
    const float* Wx    = (const float*)d_in[8];
    const float* Wh    = (const float*)d_in[9];
    const float* bl    = (const float*)d_in[10];
    const float* Wr    = (const float*)d_in[11];
    const float* br    = (const float*)d_in[12];
    const float* Ww    = (const float*)d_in[13];
    const float* bw    = (const float*)d_in[14];
    const float* Wo    = (const float*)d_in[15];
    const float* bo    = (const float*)d_in[16];

    float* ws = (float*)d_ws;
    // all offsets in floats, 16B-aligned
    u16*   Wt_lstm = (u16*)(ws + 0);          // 2048*1056 u16 = 1,081,344 f
    u16*   Wt_h    = (u16*)(ws + 1081344);    // 384*512  u16 = 98,304 f
    u16*   Wt_o    = (u16*)(ws + 1179648);    // 512*576  u16 = 147,456 f
    u16*   Abuf    = (u16*)(ws + 1327104);    // 2048*1056 u16 = 1,081,344 f
    u16*   A2      = (u16*)(ws + 2408448);    // 2048*576 u16 = 589,824 f
    float* z       =        ws + 2998272;     // 2048*2048 f
    float* rout    =        ws + 7192576;     // 2048*70
    float* wout    =        ws + 7335936;     // 2048*198
    // total ~7.74M floats = 31 MB

    float* out    = (float*)d_out;
    float* out_y  = out;              // 1048576
    float* out_mt = out + 1048576;    // 33554432
    float* out_rt = out + 34603008;   // 131072
    float* out_wr = out + 34734080;   // 524288
    float* out_ww = out + 35258368;   // 524288

    hipLaunchKernelGGL(k_wt_lstm,  dim3(64,33), dim3(256), 0, stream, Wx, Wh, Wt_lstm);
    hipLaunchKernelGGL(k_wt_heads, dim3(12,16), dim3(256), 0, stream, Wr, Ww, Wt_h);
    hipLaunchKernelGGL(k_wt_out,   dim3(16,18), dim3(256), 0, stream, Wo, Wt_o);
    hipLaunchKernelGGL(k_abuild,   dim3(4096),  dim3(256), 0, stream, x, H0, R0, Wprep, bprep, Abuf);
    hipLaunchKernelGGL(k_gemm_lstm, dim3(16,16), dim3(256), 0, stream, Abuf, Wt_lstm, z);
    hipLaunchKernelGGL(k_gates,    dim3(4096),  dim3(256), 0, stream, z, C0, bl, A2);
    hipLaunchKernelGGL(k_gemm_heads, dim3(16,3), dim3(256), 0, stream, A2, Wt_h, br, bw, rout, wout);
    hipLaunchKernelGGL(k_addr,     dim3(2048),  dim3(256), 0, stream, m0, A0, rout, wout, A2,
                       out_mt, out_rt, out_wr, out_ww);
    hipLaunchKernelGGL(k_gemm_out, dim3(16,4),  dim3(256), 0, stream, A2, Wt_o, bo, out_y);
}